// Round 5
// baseline (228.971 us; speedup 1.0000x reference)
//
#include <hip/hip_runtime.h>

typedef __bf16 bfrag __attribute__((ext_vector_type(8)));
typedef __bf16 bh4 __attribute__((ext_vector_type(4)));
typedef float f4 __attribute__((ext_vector_type(4)));

#define AS1C(p) (const __attribute__((address_space(1))) void*)(p)
#define AS3(p)  (__attribute__((address_space(3))) void*)(p)

// 0.125 (=1/sqrt(64)) * log2(e): folded into Q so softmax is a bare exp2
#define QSCALE 0.18033688011112042f

__device__ __forceinline__ void g2l16(const __bf16* g, __bf16* l) {
  __builtin_amdgcn_global_load_lds(AS1C(g), AS3(l), 16, 0, 0);
}

// ---------- f32 -> bf16 bulk convert: x + 4 weights in one dispatch ----------
__global__ __launch_bounds__(256) void cvt5(
    const float* __restrict__ s0, const float* __restrict__ s1,
    const float* __restrict__ s2, const float* __restrict__ s3,
    const float* __restrict__ s4,
    __bf16* __restrict__ d0, __bf16* __restrict__ d1, __bf16* __restrict__ d2,
    __bf16* __restrict__ d3, __bf16* __restrict__ d4, long n0, long n1) {
  const float* s; __bf16* d; long n;
  switch (blockIdx.y) {
    case 0: s = s0; d = d0; n = n0; break;
    case 1: s = s1; d = d1; n = n1; break;
    case 2: s = s2; d = d2; n = n1; break;
    case 3: s = s3; d = d3; n = n1; break;
    default: s = s4; d = d4; n = n1; break;
  }
  long i = ((long)blockIdx.x * 256 + threadIdx.x) * 8;
  if (i >= n) return;
  float4 a = *(const float4*)(s + i);
  float4 b = *(const float4*)(s + i + 4);
  bfrag o;
  o[0] = (__bf16)a.x; o[1] = (__bf16)a.y; o[2] = (__bf16)a.z; o[3] = (__bf16)a.w;
  o[4] = (__bf16)b.x; o[5] = (__bf16)b.y; o[6] = (__bf16)b.z; o[7] = (__bf16)b.w;
  *(bfrag*)(d + i) = o;
}

#define BARR __builtin_amdgcn_s_barrier()
#define WAIT_LGKM { asm volatile("s_waitcnt lgkmcnt(0)" ::: "memory"); \
                    __builtin_amdgcn_sched_barrier(0); }
#define WAIT_VM(N) asm volatile("s_waitcnt vmcnt(" #N ")" ::: "memory")

// ======== L2-working-set GEMM: 256x128 tile, triple-buffered BK=64 =========
// Theory (r5): all schedules hit ~770 TF because staging feeds from L3
// (~10 B/cyc/CU). Fix the XCD working set to exactly its 4 MB L2:
// each XCD owns 4 fixed bm-panels (A = 2 MB, resident for the whole
// kernel) and marches bn; per round its 32 blocks = 4bm x 8bn -> +2 MB
// of B = 4 MB total. Loop = round-3-proven triple-buffer (soak >= 1 full
// tile-compute), vmcnt(6), T2 swizzle. MODE 0: QKV epilogue (Q/K scaled
// store, V kappa' transpose); grid 768 = 3 rounds, bnq = 8*round + ...
// MODE 1: f32 C (projection); grid 256 = 1 exact round.
template <int MODE>
__global__ __launch_bounds__(512, 2) void gemm_l2(
    const __bf16* __restrict__ A, const __bf16* __restrict__ Bw,
    __bf16* __restrict__ qb, __bf16* __restrict__ kb,
    __bf16* __restrict__ vt, float* __restrict__ Cf, int K) {
  __shared__ __bf16 lds[73728];          // A: 3x16384 | B: 3x8192 (144 KiB)
  __bf16* ldsA = lds;
  __bf16* ldsB = lds + 49152;
  const int tid = threadIdx.x;
  const int wave = tid >> 6, lane = tid & 63;
  const int lm = lane & 15, quad = lane >> 4;
  const int wm = wave >> 1, wn = wave & 1;   // 4m x 2n waves, 64x64 each
  // XCD-resident remap: hw linear id % 8 = XCD round-robin
  const int l = blockIdx.x;
  const int xcd = l & 7;
  int bm, bnq;
  if (MODE == 0) {
    const int r = l >> 3;                // 0..95
    const int pos = r & 31, rnd = r >> 5;
    bm = xcd * 4 + (pos & 3);            // 0..31 (fixed per XCD)
    bnq = (pos >> 2) + rnd * 8;          // 0..23 (128-wide panels)
  } else {
    const int pos = l >> 3;              // 0..31
    bm = xcd * 4 + (pos & 3);
    bnq = pos >> 2;                      // 0..7
  }
  const long bmr = (long)bm * 256;
  const long bnr = (long)bnq * 128;
  const int scol = ((tid & 7) ^ ((tid >> 3) & 7)) * 8;  // pre-swizzled src col
  const int rsw = lm & 7;                               // read swizzle key

// stage one 256x64 A-tile (4 g2l16) + 128x64 B-tile (2 g2l16) into slot sl
#define STG(sl, kt) { \
    _Pragma("unroll") for (int j_ = 0; j_ < 4; ++j_) \
      g2l16(A + (bmr + j_ * 64 + (tid >> 3)) * K + (kt) * 64 + scol, \
            ldsA + (sl) * 16384 + j_ * 4096 + tid * 8); \
    _Pragma("unroll") for (int j_ = 0; j_ < 2; ++j_) \
      g2l16(Bw + (bnr + j_ * 64 + (tid >> 3)) * K + (kt) * 64 + scol, \
            ldsB + (sl) * 8192 + j_ * 4096 + tid * 8); }

// one k-half (K=32) of the wave's 64x64 tile: 8 ds_read_b128, 16 MFMA
#define KHALF(sl, kk) { \
    const __bf16* Ab_ = ldsA + (sl) * 16384 + (wm * 64 + lm) * 64; \
    const __bf16* Bb_ = ldsB + (sl) * 8192 + (wn * 64 + lm) * 64; \
    bfrag af_[4], bg_[4]; \
    _Pragma("unroll") for (int j_ = 0; j_ < 4; ++j_) \
      af_[j_] = *(const bfrag*)(Ab_ + j_ * 1024 + (((kk) * 4 + quad) ^ rsw) * 8); \
    _Pragma("unroll") for (int n_ = 0; n_ < 4; ++n_) \
      bg_[n_] = *(const bfrag*)(Bb_ + n_ * 1024 + (((kk) * 4 + quad) ^ rsw) * 8); \
    WAIT_LGKM; \
    __builtin_amdgcn_s_setprio(1); \
    _Pragma("unroll") for (int j_ = 0; j_ < 4; ++j_) \
      _Pragma("unroll") for (int n_ = 0; n_ < 4; ++n_) \
        acc[j_][n_] = __builtin_amdgcn_mfma_f32_16x16x32_bf16( \
            af_[j_], bg_[n_], acc[j_][n_], 0, 0, 0); \
    __builtin_amdgcn_s_setprio(0); }

  f4 acc[4][4] = {};
  const int ntiles = K >> 6;   // 16
  // prologue: stage tiles 0,1; drain tile 0 (tile 1 keeps soaking)
  STG(0, 0);
  STG(1, 1);
  WAIT_VM(6);
  BARR;
#pragma unroll 1
  for (int t = 0; t < ntiles; ++t) {
    const int sl = t % 3;
    if (t + 2 < ntiles) { const int s2 = (t + 2) % 3; STG(s2, t + 2); }
    KHALF(sl, 0);
    KHALF(sl, 1);
    if (t + 2 < ntiles) { WAIT_VM(6); } else { WAIT_VM(0); }
    BARR;
  }

  if (MODE == 1) {
    // projection: f32 C (N = 1024)
#pragma unroll
    for (int mi = 0; mi < 4; ++mi)
#pragma unroll
      for (int ni = 0; ni < 4; ++ni)
#pragma unroll
        for (int r = 0; r < 4; ++r) {
          long row = bmr + wm * 64 + mi * 16 + quad * 4 + r;
          long col = bnr + wn * 64 + ni * 16 + lm;
          Cf[row * 1024 + col] = acc[mi][ni][r];
        }
  } else if (bnq < 16) {
    __bf16* dst = (bnq < 8) ? qb : kb;
    const float scl = (bnq < 8) ? QSCALE : 1.0f;
    const int nb = (bnq & 7) * 128;
#pragma unroll
    for (int mi = 0; mi < 4; ++mi)
#pragma unroll
      for (int ni = 0; ni < 4; ++ni)
#pragma unroll
        for (int r = 0; r < 4; ++r) {
          long row = bmr + wm * 64 + mi * 16 + quad * 4 + r;
          long col = nb + wn * 64 + ni * 16 + lm;
          dst[row * 1024 + col] = (__bf16)(acc[mi][ni][r] * scl);
        }
  } else {
    // V: acc(row=t, col=d) -> vt[d][t'], t' = (t>>6)*64 + kappa'(t&63),
    // kappa'(u) = (u&15)*4 + (u>>4). One pass: lds[128][260] transpose.
#pragma unroll
    for (int mi = 0; mi < 4; ++mi)
#pragma unroll
      for (int ni = 0; ni < 4; ++ni)
#pragma unroll
        for (int r = 0; r < 4; ++r) {
          int d = wn * 64 + ni * 16 + lm;                    // 0..127
          int tp = wm * 64 + (quad * 4 + r) * 4 + mi;        // 0..255
          lds[d * 260 + tp] = (__bf16)acc[mi][ni][r];
        }
    __syncthreads();
    const int bloc = bm >> 3;
    const int tbase = (bm & 7) * 256;
    const long dbase = bnr - 2048;
#pragma unroll
    for (int p = 0; p < 4; ++p) {
      int d = (tid >> 4) + p * 32;                           // 0..127
#pragma unroll
      for (int c2 = 0; c2 < 2; ++c2) {
        int c = (tid & 15) * 16 + c2 * 8;                    // 0..255
        *(bfrag*)(vt + ((long)bloc * 1024 + dbase + d) * 2048 + tbase + c) =
            *(const bfrag*)(lds + d * 260 + c);
      }
    }
  }
}

// ---------- fallback GEMM (f32 A / f32 B, inline convert) ----------
template <bool A_F32, bool OUT_F32>
__global__ __launch_bounds__(256) void gemm_bt_cv(
    const void* __restrict__ Ap, const float* __restrict__ Bp,
    void* __restrict__ Cp, int M, int N, int K, float scl) {
  __shared__ __bf16 As[128 * 32];
  __shared__ __bf16 Bs[128 * 32];
  const int tid = threadIdx.x;
  const int lane = tid & 63, wave = tid >> 6;
  const int lm = lane & 15, quad = lane >> 4;
  const int bm = blockIdx.x * 128, bn = blockIdx.y * 128;
  const int wr = (wave >> 1) * 64, wc = (wave & 1) * 64;
  const int e0 = tid * 16, sr = e0 >> 5, sc = e0 & 31;
  f4 acc[4][4] = {};
  for (int k0 = 0; k0 < K; k0 += 32) {
    if (A_F32) {
      const float4* ga = (const float4*)((const float*)Ap + (long)(bm + sr) * K + k0 + sc);
#pragma unroll
      for (int j = 0; j < 4; ++j) {
        float4 v = ga[j];
        As[sr * 32 + sc + j * 4 + 0] = (__bf16)v.x;
        As[sr * 32 + sc + j * 4 + 1] = (__bf16)v.y;
        As[sr * 32 + sc + j * 4 + 2] = (__bf16)v.z;
        As[sr * 32 + sc + j * 4 + 3] = (__bf16)v.w;
      }
    } else {
      const __bf16* Ab = (const __bf16*)Ap + (long)(bm + sr) * K + k0 + sc;
      *(bfrag*)(As + sr * 32 + sc) = *(const bfrag*)Ab;
      *(bfrag*)(As + sr * 32 + sc + 8) = *(const bfrag*)(Ab + 8);
    }
    {
      const float4* gb = (const float4*)(Bp + (long)(bn + sr) * K + k0 + sc);
#pragma unroll
      for (int j = 0; j < 4; ++j) {
        float4 v = gb[j];
        Bs[sr * 32 + sc + j * 4 + 0] = (__bf16)v.x;
        Bs[sr * 32 + sc + j * 4 + 1] = (__bf16)v.y;
        Bs[sr * 32 + sc + j * 4 + 2] = (__bf16)v.z;
        Bs[sr * 32 + sc + j * 4 + 3] = (__bf16)v.w;
      }
    }
    __syncthreads();
    bfrag af[4], bg[4];
#pragma unroll
    for (int mi = 0; mi < 4; ++mi)
      af[mi] = *(const bfrag*)(As + (wr + mi * 16 + lm) * 32 + quad * 8);
#pragma unroll
    for (int ni = 0; ni < 4; ++ni)
      bg[ni] = *(const bfrag*)(Bs + (wc + ni * 16 + lm) * 32 + quad * 8);
#pragma unroll
    for (int mi = 0; mi < 4; ++mi)
#pragma unroll
      for (int ni = 0; ni < 4; ++ni)
        acc[mi][ni] = __builtin_amdgcn_mfma_f32_16x16x32_bf16(af[mi], bg[ni], acc[mi][ni], 0, 0, 0);
    __syncthreads();
  }
#pragma unroll
  for (int mi = 0; mi < 4; ++mi)
#pragma unroll
    for (int ni = 0; ni < 4; ++ni)
#pragma unroll
      for (int r = 0; r < 4; ++r) {
        long row = bm + wr + mi * 16 + quad * 4 + r;
        long col = bn + wc + ni * 16 + lm;
        if (OUT_F32) ((float*)Cp)[row * N + col] = acc[mi][ni][r] * scl;
        else ((__bf16*)Cp)[row * N + col] = (__bf16)(acc[mi][ni][r] * scl);
      }
}

// ---------- flash attention v8: 128-row q-tiles, 4 frags/wave ----------
#define KP 72

template <bool VT>
__global__ __launch_bounds__(256, 2) void attn_fwd8(
    const __bf16* Qg, const __bf16* __restrict__ Kg,
    const __bf16* __restrict__ Vsrc, __bf16* Yg) {
  const int TT = 2048, CC = 1024;
  __shared__ __bf16 Ks[64 * KP];
  __shared__ __bf16 Vs[64 * KP];
  __shared__ __bf16 Ps[16 * 16 * KP];
  const int tid = threadIdx.x;
  const int wave = tid >> 6, lane = tid & 63;
  const int lm = lane & 15, quad = lane >> 4;
  const int bh = blockIdx.x, i = blockIdx.y;
  const int b = bh >> 4, h = bh & 15;
  const int qtA = i, qtB = 15 - i;
  const long rbase = (long)b * TT;
  const int hoff = h * 64;
  int row0[4];
  row0[0] = qtA * 128 + wave * 16;
  row0[1] = qtA * 128 + 64 + wave * 16;
  row0[2] = qtB * 128 + wave * 16;
  row0[3] = qtB * 128 + 64 + wave * 16;
  __bf16* Pw[4];
#pragma unroll
  for (int fr = 0; fr < 4; ++fr) Pw[fr] = Ps + (wave * 4 + fr) * 16 * KP;
  bfrag qf[4][2];
#pragma unroll
  for (int fr = 0; fr < 4; ++fr)
#pragma unroll
    for (int f = 0; f < 2; ++f)
      qf[fr][f] = *(const bfrag*)(Qg + (rbase + row0[fr] + lm) * CC + hoff + f * 32 + quad * 8);
  bfrag ones;
#pragma unroll
  for (int j = 0; j < 8; ++j) ones[j] = (__bf16)1.0f;
  f4 y[4][4] = {};
  f4 L[4] = {};

  const int ktLast = 2 * qtB + 1;
  bfrag kin[2], vin[2];
#pragma unroll
  for (int s = 0; s < 2; ++s) {
    int idx = tid + s * 256;
    int r = idx >> 3, c = (idx & 7) * 8;
    kin[s] = *(const bfrag*)(Kg + (rbase + r) * CC + hoff + c);
    if (VT)
      vin[s] = *(const bfrag*)(Vsrc + ((long)b * 1024 + hoff + r) * 2048 + c);
    else
      vin[s] = *(const bfrag*)(Vsrc + (rbase + r) * CC + hoff + c);
  }

  for (int kt = 0; kt <= ktLast; ++kt) {
    const int kBase = kt * 64;
    __syncthreads();
#pragma unroll
    for (int s = 0; s < 2; ++s) {
      int idx = tid + s * 256;
      int r = idx >> 3, c = (idx & 7) * 8;
      *(bfrag*)(Ks + r * KP + c) = kin[s];
      if (VT) {
        *(bfrag*)(Vs + r * KP + c) = vin[s];
      } else {
        int kp = (r & 15) * 4 + (r >> 4);
#pragma unroll
        for (int j = 0; j < 8; ++j) Vs[(c + j) * KP + kp] = vin[s][j];
      }
    }
    const bool more = (kt < ktLast);
    bfrag kin2[2], vin2[2];
    if (more) {
      const int nB = kBase + 64;
#pragma unroll
      for (int s = 0; s < 2; ++s) {
        int idx = tid + s * 256;
        int r = idx >> 3, c = (idx & 7) * 8;
        kin2[s] = *(const bfrag*)(Kg + (rbase + nB + r) * CC + hoff + c);
        if (VT)
          vin2[s] = *(const bfrag*)(Vsrc + ((long)b * 1024 + hoff + r) * 2048 + nB + c);
        else
          vin2[s] = *(const bfrag*)(Vsrc + (rbase + nB + r) * CC + hoff + c);
      }
    }
    __syncthreads();
    bfrag kf[8];
#pragma unroll
    for (int sub = 0; sub < 4; ++sub)
#pragma unroll
      for (int f = 0; f < 2; ++f)
        kf[sub * 2 + f] = *(const bfrag*)(Ks + (sub * 16 + lm) * KP + f * 32 + quad * 8);
#pragma unroll
    for (int fr = 0; fr < 4; ++fr) {
      if (kBase <= row0[fr] + 15) {
        f4 sac[4];
#pragma unroll
        for (int sub = 0; sub < 4; ++sub) {
          f4 z = {};
#pragma unroll
          for (int f = 0; f < 2; ++f)
            z = __builtin_amdgcn_mfma_f32_16x16x32_bf16(qf[fr][f], kf[sub * 2 + f], z, 0, 0, 0);
          sac[sub] = z;
        }
        if (kBase + 63 > row0[fr]) {
#pragma unroll
          for (int r = 0; r < 4; ++r) {
            bh4 pk;
#pragma unroll
            for (int sub = 0; sub < 4; ++sub) {
              float pv = __builtin_amdgcn_exp2f(sac[sub][r]);
              bool masked = (kBase + sub * 16 + lm > row0[fr] + quad * 4 + r);
              pk[sub] = (__bf16)(masked ? 0.f : pv);
            }
            *(bh4*)(Pw[fr] + (quad * 4 + r) * KP + lm * 4) = pk;
          }
        } else {
#pragma unroll
          for (int r = 0; r < 4; ++r) {
            bh4 pk;
#pragma unroll
            for (int sub = 0; sub < 4; ++sub)
              pk[sub] = (__bf16)__builtin_amdgcn_exp2f(sac[sub][r]);
            *(bh4*)(Pw[fr] + (quad * 4 + r) * KP + lm * 4) = pk;
          }
        }
      }
    }
    __asm__ volatile("s_waitcnt lgkmcnt(0)" ::: "memory");
    bfrag vf[8];
#pragma unroll
    for (int sub = 0; sub < 4; ++sub)
#pragma unroll
      for (int f = 0; f < 2; ++f)
        vf[sub * 2 + f] = *(const bfrag*)(Vs + (sub * 16 + lm) * KP + f * 32 + quad * 8);
#pragma unroll
    for (int fr = 0; fr < 4; ++fr) {
      if (kBase <= row0[fr] + 15) {
#pragma unroll
        for (int f = 0; f < 2; ++f) {
          bfrag pf = *(const bfrag*)(Pw[fr] + lm * KP + f * 32 + quad * 8);
          L[fr] = __builtin_amdgcn_mfma_f32_16x16x32_bf16(pf, ones, L[fr], 0, 0, 0);
#pragma unroll
          for (int ds = 0; ds < 4; ++ds)
            y[fr][ds] = __builtin_amdgcn_mfma_f32_16x16x32_bf16(pf, vf[ds * 2 + f], y[fr][ds], 0, 0, 0);
        }
      }
    }
    if (more) {
      kin[0] = kin2[0]; kin[1] = kin2[1];
      vin[0] = vin2[0]; vin[1] = vin2[1];
    }
  }
#pragma unroll
  for (int fr = 0; fr < 4; ++fr)
#pragma unroll
    for (int ds = 0; ds < 4; ++ds)
#pragma unroll
      for (int r = 0; r < 4; ++r) {
        long row = rbase + row0[fr] + quad * 4 + r;
        Yg[row * CC + hoff + ds * 16 + lm] = (__bf16)(y[fr][ds][r] / L[fr][r]);
      }
}

extern "C" void kernel_launch(void* const* d_in, const int* in_sizes, int n_in,
                              void* d_out, int out_size, void* d_ws, size_t ws_size,
                              hipStream_t stream) {
  (void)in_sizes; (void)n_in; (void)out_size;
  const float* x  = (const float*)d_in[0];
  const float* Wq = (const float*)d_in[1];
  const float* Wk = (const float*)d_in[2];
  const float* Wv = (const float*)d_in[3];
  const float* Wp = (const float*)d_in[4];
  float* out = (float*)d_out;
  const long R = 8192;             // B*T
  const long BUF = R * 1024;
  const long WN = 1024L * 1024;
  __bf16* qb = (__bf16*)d_ws;      // q (pre-scaled), then y in-place
  __bf16* kb = (__bf16*)d_out;     // k + vt borrow d_out (dead before final GEMM)
  __bf16* vslot = kb + BUF;
  dim3 blk(256, 1, 1);
  const size_t need = (size_t)(2 * BUF + 4 * WN) * 2;
  if (ws_size >= need) {
    __bf16* xb = qb + BUF;
    __bf16* wqkv = xb + BUF;       // Wq,Wk,Wv contiguous = [3072][1024]
    __bf16* wpb = wqkv + 3 * WN;
    cvt5<<<dim3((unsigned)(BUF / (256 * 8)), 5, 1), blk, 0, stream>>>(
        x, Wq, Wk, Wv, Wp, xb, wqkv, wqkv + WN, wqkv + 2 * WN, wpb, BUF, WN);
    gemm_l2<0><<<dim3(768, 1, 1), dim3(512, 1, 1), 0, stream>>>(
        xb, wqkv, qb, kb, vslot, nullptr, 1024);
    attn_fwd8<true><<<dim3(64, 8, 1), blk, 0, stream>>>(qb, kb, vslot, qb);
    gemm_l2<1><<<dim3(256, 1, 1), dim3(512, 1, 1), 0, stream>>>(
        qb, wpb, nullptr, nullptr, nullptr, out, 1024);
  } else {
    gemm_bt_cv<true, false><<<dim3(64, 8, 1), blk, 0, stream>>>(x, Wq, qb, 8192, 1024, 1024, QSCALE);
    gemm_bt_cv<true, false><<<dim3(64, 8, 1), blk, 0, stream>>>(x, Wk, kb, 8192, 1024, 1024, 1.0f);
    gemm_bt_cv<true, false><<<dim3(64, 8, 1), blk, 0, stream>>>(x, Wv, vslot, 8192, 1024, 1024, 1.0f);
    attn_fwd8<false><<<dim3(64, 8, 1), blk, 0, stream>>>(qb, kb, vslot, qb);
    gemm_bt_cv<false, true><<<dim3(64, 8, 1), blk, 0, stream>>>(qb, Wp, out, 8192, 1024, 1024, 1.0f);
  }
}